// Round 10
// baseline (240.133 us; speedup 1.0000x reference)
//
#include <hip/hip_runtime.h>
#include <math.h>

// IDMPNN fused forward — R10: K=16 MFMAs => ZERO-LDS layer loop.
// With v_mfma_f32_16x16x16_f16 (A[m=lane&15][k=quad*4+j], C row=quad*4+reg),
// every producer C-layout IS the consumer operand layout (reg r <-> k j,
// m-tile <-> k-block). Chain g=h@W1 -> t^T=g^T@adjT -> u^T=W2^T@t^T -> residual
// runs entirely in registers: no LDS transposes, no barriers, no cross-lane ops
// except LayerNorm's 2 shfl_xor. LDS only for params, final 6-perm dump, tail.
// Structure else = R9: block = 2 subgraphs (same graph) x 6 waves (perm/wave),
// 2 chains/wave for ILP; fused tail + device-atomic segment-max.

#define NBATCH 64
#define NM 32
#define NS 32
#define KSUB 3
#define HID 64
#define NLAYER 4
#define PP 6

// d_ws: fp16 weight planes (ushort offsets), then byte offsets (prep unchanged)
#define W1F 0            // [l][dout][din] 16384
#define W2F 16384
#define S1F 32768        // planes end at ushort 36864 = byte 73728
#define GMAX_BYTE 73728  // uint[64*64]
#define CNT_BYTE  90112  // uint[64]
#define S2WT_BYTE 90368  // float[64*64]

#define SH 68            // dump row stride (ushorts): 32 rows x 64 fp16 + pad
#define WBU 2176         // per-chain dump buffer ushorts (32*68)

typedef _Float16 f16x4 __attribute__((ext_vector_type(4)));
typedef _Float16 f16x2 __attribute__((ext_vector_type(2)));
typedef __fp16 fp16x2 __attribute__((ext_vector_type(2)));   // cvt_pkrtz return
typedef float f32x4 __attribute__((ext_vector_type(4)));

#define MFMA16(a, b, c) __builtin_amdgcn_mfma_f32_16x16x16f16(a, b, c, 0, 0, 0)

__constant__ int c_perm[KSUB][PP] = {
    {0, 0, 1, 1, 2, 2},
    {1, 2, 0, 2, 0, 1},
    {2, 1, 2, 0, 1, 0}
};

union U2F { uint2 u; f16x4 f; };

__device__ __forceinline__ unsigned pk2rtz(float a, float b) {
    union { fp16x2 h; unsigned u; } x;
    x.h = __builtin_amdgcn_cvt_pkrtz(a, b);
    return x.u;
}
__device__ __forceinline__ uint2 pk4rtz(float a, float b, float c, float d) {
    return make_uint2(pk2rtz(a, b), pk2rtz(c, d));
}
__device__ __forceinline__ f16x4 fpk4(float a, float b, float c, float d) {
    U2F x; x.u = pk4rtz(a, b, c, d); return x.f;
}
__device__ __forceinline__ f16x4 asf(uint2 u) { U2F x; x.u = u; return x.f; }
__device__ __forceinline__ unsigned pkadd(unsigned hu, unsigned yu) {
    union { f16x2 h; unsigned u; } a, b;
    a.u = hu; b.u = yu;
    a.h = a.h + b.h;            // v_pk_add_f16
    return a.u;
}
__device__ __forceinline__ float2 upk2(unsigned u) {
    union { unsigned u; _Float16 h[2]; } x; x.u = u;
    return make_float2((float)x.h[0], (float)x.h[1]);
}

// ---- prep: fp16 weight planes [l][dout][din] + s2w^T f32 + zero gmax/cnt ----
extern "C" __global__ void idmpnn_prep(const float* __restrict__ w1,
                                       const float* __restrict__ w2,
                                       const float* __restrict__ s1w,
                                       const float* __restrict__ s2w,
                                       char* __restrict__ ws)
{
    unsigned short* wsu = (unsigned short*)ws;
    int idx = blockIdx.x * 256 + threadIdx.x;
    float v; int dst;
    if (idx < 16384) {
        int l = idx >> 12, r = idx & 4095, dp = r >> 6, e = r & 63;
        v = w1[l * 4096 + e * 64 + dp];
        dst = W1F + idx;
    } else if (idx < 32768) {
        int k = idx - 16384;
        int l = k >> 12, r = k & 4095, dp = r >> 6, e = r & 63;
        v = w2[l * 4096 + e * 64 + dp];
        dst = W2F + k;
    } else if (idx < 36864) {
        int k = idx - 32768, dp = k >> 6, e = k & 63;
        v = s1w[e * 64 + dp];
        dst = S1F + k;
    } else if (idx < 40960) {
        int k = idx - 36864, dp = k >> 6, e = k & 63;
        ((float*)(ws + S2WT_BYTE))[k] = s2w[e * 64 + dp];
        return;
    } else if (idx < 45056) {
        ((unsigned*)(ws + GMAX_BYTE))[idx - 40960] = 0u;
        return;
    } else if (idx < 45120) {
        ((unsigned*)(ws + CNT_BYTE))[idx - 45056] = 0u;
        return;
    } else return;
    union { _Float16 h; unsigned short u; } cv;
    cv.h = (_Float16)v;                 // RNE once
    wsu[dst] = cv.u;
}

extern "C" __global__ void __launch_bounds__(384, 2)
idmpnn_main(const int* __restrict__ xg, const float* __restrict__ subadj,
            const int* __restrict__ subgs, const int* __restrict__ num_node,
            const float* __restrict__ idemb, const float* __restrict__ node_emb,
            const float* __restrict__ b1g, const float* __restrict__ b2g,
            const float* __restrict__ lngm, const float* __restrict__ lnbm,
            const float* __restrict__ s1bm, const float* __restrict__ s2bm,
            const float* __restrict__ outw, const float* __restrict__ outb,
            const unsigned short* __restrict__ wsf, const float* __restrict__ s2wt,
            unsigned* __restrict__ gmax, unsigned* __restrict__ cnt,
            float* __restrict__ out)
{
    // 52224 + 768 + 4096 + 512 = 57600 B LDS
    __shared__ unsigned short WB[12 * WBU];  // [wave][chain] final-h dump only
    __shared__ float idS[KSUB * 64];
    __shared__ float prm[NLAYER * 4 * 64];   // b1,b2,g,be per layer
    __shared__ float HSf[2 * HID];

    const int s0 = blockIdx.x * 2;           // subgraphs s0, s0+1 (same graph)
    const int b = s0 >> 5;
    const int tid = threadIdx.x;
    const int w = tid / 64, lane = tid & 63; // w = perm id 0..5
    const int c = lane & 15, q = lane >> 4;

    for (int t = tid; t < NLAYER * 4 * 64; t += 384) {
        int l = t >> 8, r2 = t & 255, set = r2 >> 6, d = r2 & 63;
        const float* src = (set == 0) ? b1g : (set == 1) ? b2g : (set == 2) ? lngm : lnbm;
        prm[t] = src[l * HID + d];
    }
    if (tid < KSUB * 64) idS[tid] = idemb[tid];

    int nd[2][3];
#pragma unroll
    for (int ch = 0; ch < 2; ++ch)
#pragma unroll
        for (int k = 0; k < 3; ++k)
            nd[ch][k] = subgs[(s0 + ch) * KSUB + k];
    const int nn = num_node[b];
    const int zi0 = xg[b * NM + c];
    const int zi1 = xg[b * NM + 16 + c];

    // adjacency B-frags (K16): adjb[in][kb] = adj[i=in*16+c][j=kb*16+4q+0..3]
    uint2 adjb[2][2];
#pragma unroll
    for (int in_ = 0; in_ < 2; ++in_)
#pragma unroll
        for (int kb = 0; kb < 2; ++kb) {
            float4 f = *(const float4*)(subadj + (size_t)b * NM * NM
                                        + (in_ * 16 + c) * NM + kb * 16 + 4 * q);
            adjb[in_][kb] = pk4rtz(f.x, f.y, f.z, f.w);
        }

    __syncthreads();

    unsigned short* wbc[2] = { WB + (w * 2 + 0) * WBU, WB + (w * 2 + 1) * WBU };
    const int p = w;

    // h packed 2xfp16: hpk[ch][in*8+dm*2+g2] = h[i=in*16+c][d=dm*16+4q+2g2+{0,1}]
    // == next GEMM-A A-frag [mtile=in][kblk=dm] (K16 layout). Persistent regs.
    unsigned hpk[2][16];
#pragma unroll
    for (int in_ = 0; in_ < 2; ++in_) {
        int i = in_ * 16 + c;
        int z = in_ ? zi1 : zi0;
        int pid[2];
#pragma unroll
        for (int ch = 0; ch < 2; ++ch)
            pid[ch] = (i == nd[ch][0]) ? c_perm[0][p] : (i == nd[ch][1]) ? c_perm[1][p]
                      : (i == nd[ch][2]) ? c_perm[2][p] : -1;
#pragma unroll
        for (int dm = 0; dm < 4; ++dm) {
            float4 e4 = *(const float4*)(node_emb + (size_t)z * HID + dm * 16 + 4 * q);
#pragma unroll
            for (int ch = 0; ch < 2; ++ch) {
                float4 v = e4;
                if (pid[ch] >= 0) {
                    float4 f4 = *(const float4*)&idS[pid[ch] * 64 + dm * 16 + 4 * q];
                    v.x *= f4.x; v.y *= f4.y; v.z *= f4.z; v.w *= f4.w;
                }
                uint2 u = pk4rtz(v.x, v.y, v.z, v.w);
                hpk[ch][in_ * 8 + dm * 2 + 0] = u.x;
                hpk[ch][in_ * 8 + dm * 2 + 1] = u.y;
            }
        }
    }

#pragma unroll 1
    for (int l = 0; l < NLAYER; ++l) {
        // ---- GEMM-A: g = h @ W1  (m=i, n=d', k=d; 4 K16 blocks) ----
        // output gg C-layout == GEMM-B A-frag [kblk=im][mtile=jn]; pack -> gpk
        uint2 gpk[2][2][4];   // [ch][im(=kblk next)][jn(=mtile next)]
#pragma unroll
        for (int jn = 0; jn < 4; ++jn) {
            uint2 w1f[4];
#pragma unroll
            for (int kb = 0; kb < 4; ++kb)
                w1f[kb] = *(const uint2*)(wsf + W1F + (l * 64 + jn * 16 + c) * 64
                                          + kb * 16 + 4 * q);
#pragma unroll
            for (int ch = 0; ch < 2; ++ch)
#pragma unroll
                for (int im = 0; im < 2; ++im) {
                    f32x4 acc = {0.f, 0.f, 0.f, 0.f};
#pragma unroll
                    for (int kb = 0; kb < 4; ++kb)
                        acc = MFMA16(asf(make_uint2(hpk[ch][im * 8 + kb * 2],
                                                    hpk[ch][im * 8 + kb * 2 + 1])),
                                     asf(w1f[kb]), acc);
                    gpk[ch][im][jn] = pk4rtz(acc[0], acc[1], acc[2], acc[3]);
                }
        }

        // ---- GEMM-B: t^T = g^T @ adjT  (m=d', n=i, k=j; A-frag = gpk) ----
        // output tt C-layout == GEMM-C B-frag [kblk=dmA][ntile=in]; relu(+b1)
        uint2 tpk[2][4][2];   // [ch][dmA(=kblk next)][in(=ntile next)]
#pragma unroll
        for (int dmA = 0; dmA < 4; ++dmA) {
            float4 b1v = *(const float4*)&prm[(l * 4 + 0) * 64 + dmA * 16 + 4 * q];
#pragma unroll
            for (int ch = 0; ch < 2; ++ch)
#pragma unroll
                for (int in_ = 0; in_ < 2; ++in_) {
                    f32x4 acc = {0.f, 0.f, 0.f, 0.f};
#pragma unroll
                    for (int kb = 0; kb < 2; ++kb)
                        acc = MFMA16(asf(gpk[ch][kb][dmA]), asf(adjb[in_][kb]), acc);
                    tpk[ch][dmA][in_] = pk4rtz(fmaxf(acc[0] + b1v.x, 0.f),
                                               fmaxf(acc[1] + b1v.y, 0.f),
                                               fmaxf(acc[2] + b1v.z, 0.f),
                                               fmaxf(acc[3] + b1v.w, 0.f));
                }
        }

        // ---- GEMM-C': u^T = W2^T @ t^T  (m=d, n=i, k=d'; B-frag = tpk) ----
        // output u C-layout == hpk layout. + bias, LN over d, relu, residual.
#pragma unroll
        for (int in_ = 0; in_ < 2; ++in_)
#pragma unroll
            for (int ch = 0; ch < 2; ++ch) {
                float v[16];
                float s1 = 0.f, s2 = 0.f;
#pragma unroll
                for (int dm = 0; dm < 4; ++dm) {
                    f32x4 acc = {0.f, 0.f, 0.f, 0.f};
#pragma unroll
                    for (int kb = 0; kb < 4; ++kb) {
                        uint2 w2f = *(const uint2*)(wsf + W2F + (l * 64 + dm * 16 + c) * 64
                                                    + kb * 16 + 4 * q);
                        acc = MFMA16(asf(w2f), asf(tpk[ch][kb][in_]), acc);
                    }
                    float4 b2v = *(const float4*)&prm[(l * 4 + 1) * 64 + dm * 16 + 4 * q];
                    const float* bb = (const float*)&b2v;
#pragma unroll
                    for (int r = 0; r < 4; ++r) {
                        float x = acc[r] + bb[r];
                        v[dm * 4 + r] = x;
                        s1 += x;
                        s2 += x * x;
                    }
                }
                s1 += __shfl_xor(s1, 16, 64); s1 += __shfl_xor(s1, 32, 64);
                s2 += __shfl_xor(s2, 16, 64); s2 += __shfl_xor(s2, 32, 64);
                float mean = s1 * (1.0f / HID);
                float var  = s2 * (1.0f / HID) - mean * mean;
                float rs   = rsqrtf(var + 1e-5f);
#pragma unroll
                for (int dm = 0; dm < 4; ++dm) {
                    float4 gv4  = *(const float4*)&prm[(l * 4 + 2) * 64 + dm * 16 + 4 * q];
                    float4 bev4 = *(const float4*)&prm[(l * 4 + 3) * 64 + dm * 16 + 4 * q];
                    const float* gp = (const float*)&gv4;
                    const float* bp = (const float*)&bev4;
                    float y0 = fmaxf((v[dm * 4 + 0] - mean) * rs * gp[0] + bp[0], 0.f);
                    float y1 = fmaxf((v[dm * 4 + 1] - mean) * rs * gp[1] + bp[1], 0.f);
                    float y2 = fmaxf((v[dm * 4 + 2] - mean) * rs * gp[2] + bp[2], 0.f);
                    float y3 = fmaxf((v[dm * 4 + 3] - mean) * rs * gp[3] + bp[3], 0.f);
                    int i0 = in_ * 8 + dm * 2;
                    hpk[ch][i0 + 0] = pkadd(hpk[ch][i0 + 0], pk2rtz(y0, y1));
                    hpk[ch][i0 + 1] = pkadd(hpk[ch][i0 + 1], pk2rtz(y2, y3));
                }
            }
    }

    // ---- dump final h (fp16 [i][d]) into per-chain LDS buffers ----
#pragma unroll
    for (int ch = 0; ch < 2; ++ch)
#pragma unroll
        for (int in_ = 0; in_ < 2; ++in_)
#pragma unroll
            for (int dm = 0; dm < 4; ++dm)
                *(uint2*)(wbc[ch] + (in_ * 16 + c) * SH + dm * 16 + 4 * q) =
                    make_uint2(hpk[ch][in_ * 8 + dm * 2], hpk[ch][in_ * 8 + dm * 2 + 1]);
    __syncthreads();

    // ---- tail: wave 0 -> subgraph s0, wave 1 -> s0+1 ----
    if (w < 2) {
        // combine 6 perms -> K16 A-frags mah[im][kb]
        f16x4 mah[2][4];
#pragma unroll
        for (int im = 0; im < 2; ++im) {
            float sc = ((im * 16 + c) < nn) ? (1.0f / PP) : 0.f;
#pragma unroll
            for (int kb = 0; kb < 4; ++kb) {
                int ro = (im * 16 + c) * SH + kb * 16 + 4 * q;
                float a0 = 0.f, a1 = 0.f, a2 = 0.f, a3 = 0.f;
#pragma unroll
                for (int wv = 0; wv < 6; ++wv) {
                    uint2 t = *(const uint2*)(WB + (wv * 2 + w) * WBU + ro);
                    float2 p0 = upk2(t.x), p1 = upk2(t.y);
                    a0 += p0.x; a1 += p0.y; a2 += p1.x; a3 += p1.y;
                }
                mah[im][kb] = fpk4(a0 * sc, a1 * sc, a2 * sc, a3 * sc);
            }
        }

        // GEMM-D: h1 = hm @ set1_W (m=i, n=dout, k=d)
        f32x4 hh[2][4];
#pragma unroll
        for (int im = 0; im < 2; ++im)
#pragma unroll
            for (int jn = 0; jn < 4; ++jn) hh[im][jn] = (f32x4){0.f, 0.f, 0.f, 0.f};
#pragma unroll
        for (int jn = 0; jn < 4; ++jn)
#pragma unroll
            for (int kb = 0; kb < 4; ++kb) {
                uint2 s1f = *(const uint2*)(wsf + S1F + (jn * 16 + c) * 64 + kb * 16 + 4 * q);
#pragma unroll
                for (int im = 0; im < 2; ++im)
                    hh[im][jn] = MFMA16(mah[im][kb], asf(s1f), hh[im][jn]);
            }
        // colsum over all 32 rows (padded rows contribute relu(s1b), as ref)
#pragma unroll
        for (int jn = 0; jn < 4; ++jn) {
            float sb = s1bm[jn * 16 + c];
            float cs = 0.f;
#pragma unroll
            for (int im = 0; im < 2; ++im)
#pragma unroll
                for (int r = 0; r < 4; ++r)
                    cs += fmaxf(hh[im][jn][r] + sb, 0.f);
            cs += __shfl_xor(cs, 16, 64);
            cs += __shfl_xor(cs, 32, 64);
            if (q == 0) HSf[w * HID + jn * 16 + c] = cs;
        }

        // h2 = relu(HS @ set2_W + s2b), lane = dout
        float acc = 0.f;
#pragma unroll
        for (int e4 = 0; e4 < 16; ++e4) {
            float4 wv = *(const float4*)&s2wt[lane * 64 + e4 * 4];
            float4 hv = *(const float4*)&HSf[w * HID + e4 * 4];
            acc += hv.x * wv.x + hv.y * wv.y + hv.z * wv.z + hv.w * wv.w;
        }
        float h2 = fmaxf(acc + s2bm[lane], 0.f);

        // pooling fold: device-scope atomicMax (h2 >= 0: uint order == float order)
        atomicMax(&gmax[b * HID + lane], __float_as_uint(h2));
        __threadfence();
        unsigned old = 0;
        if (lane == 0) old = atomicAdd(&cnt[b], 1u);
        old = __shfl(old, 0, 64);
        if (old == NS - 1) {   // last of the 32 subgraph-writers of this graph
            __threadfence();
            unsigned mbits = atomicOr(&gmax[b * HID + lane], 0u);
            float v = __uint_as_float(mbits) * outw[lane];
#pragma unroll
            for (int off = 32; off > 0; off >>= 1) v += __shfl_xor(v, off, 64);
            if (lane == 0) out[b] = v + outb[0];
        }
    }
}

extern "C" void kernel_launch(void* const* d_in, const int* in_sizes, int n_in,
                              void* d_out, int out_size, void* d_ws, size_t ws_size,
                              hipStream_t stream)
{
    const int*   xg       = (const int*)d_in[0];
    const float* subadj   = (const float*)d_in[1];
    const int*   subgs    = (const int*)d_in[2];
    const int*   num_node = (const int*)d_in[3];
    const float* idemb    = (const float*)d_in[5];
    const float* node_emb = (const float*)d_in[6];
    const float* w1       = (const float*)d_in[7];
    const float* b1       = (const float*)d_in[8];
    const float* w2       = (const float*)d_in[9];
    const float* b2       = (const float*)d_in[10];
    const float* g        = (const float*)d_in[11];
    const float* be       = (const float*)d_in[12];
    const float* s1w      = (const float*)d_in[13];
    const float* s1b      = (const float*)d_in[14];
    const float* s2w      = (const float*)d_in[15];
    const float* s2b      = (const float*)d_in[16];
    const float* outw     = (const float*)d_in[17];
    const float* outb     = (const float*)d_in[18];

    char* ws = (char*)d_ws;
    unsigned short* wsf = (unsigned short*)ws;
    const float* s2wt = (const float*)(ws + S2WT_BYTE);
    unsigned* gmax = (unsigned*)(ws + GMAX_BYTE);
    unsigned* cnt  = (unsigned*)(ws + CNT_BYTE);

    idmpnn_prep<<<177, 256, 0, stream>>>(w1, w2, s1w, s2w, ws);
    idmpnn_main<<<NBATCH * NS / 2, 384, 0, stream>>>(xg, subadj, subgs, num_node,
                                          idemb, node_emb,
                                          b1, b2, g, be, s1b, s2b, outw, outb,
                                          wsf, s2wt, gmax, cnt, (float*)d_out);
}

// Round 11
// 233.354 us; speedup vs baseline: 1.0291x; 1.0291x over previous
//
#include <hip/hip_runtime.h>
#include <math.h>

// IDMPNN fused forward — R11: R9 math (K32 MFMA + per-wave LDS relayouts, the
// 139us best) repackaged into 192-thread blocks to un-quantize occupancy.
// R10 post-mortem: K16 zero-LDS doubled MFMA issue (+13us) > LDS latency saved.
// R7/R9/R10 all plateau at ~24 concurrent chains/CU (regfile-bound, ~55 VGPR
// per chain). R9's 6-wave block quantizes 16-wave/CU capacity down to 12.
// Fix: block = 3 waves x [2 perm-chains of ONE subgraph], LDS exactly 32768B;
// at 128 VGPR -> 16 waves/CU -> 5 blocks/CU -> 30 chains. (192,3) cap=170:
// no forced squeeze, no spill risk. Grid 2048 blocks.

#define NBATCH 64
#define NM 32
#define NS 32
#define KSUB 3
#define HID 64
#define NLAYER 4
#define PP 6
#define STOT (NBATCH * NS)

// d_ws: fp16 weight planes (ushort offsets), then byte offsets
#define W1F 0            // [l][dout][din] 16384
#define W2F 16384
#define S1F 32768        // planes end at ushort 36864 = byte 73728
#define GMAX_BYTE 73728  // uint[64*64]
#define CNT_BYTE  90112  // uint[64]
#define S2WT_BYTE 90368  // float[64*64]

// LDS row strides (ushorts)
#define SH 68    // HB rows (32 x 64 fp16 + pad) -> 2176 ushorts
#define SG 36    // GB rows (64 x 32 fp16 + pad) -> 2304 ushorts (8B-aligned rows)
#define WBU 2304 // per-chain buffer ushorts (4608B): max(32*68, 64*36)

typedef _Float16 f16x8 __attribute__((ext_vector_type(8)));
typedef __fp16 fp16x2 __attribute__((ext_vector_type(2)));   // cvt_pkrtz return
typedef float f32x4 __attribute__((ext_vector_type(4)));

#define MFMA16(a, b, c) __builtin_amdgcn_mfma_f32_16x16x32_f16(a, b, c, 0, 0, 0)

__constant__ int c_perm[KSUB][PP] = {
    {0, 0, 1, 1, 2, 2},
    {1, 2, 0, 2, 0, 1},
    {2, 1, 2, 0, 1, 0}
};

__device__ __forceinline__ unsigned pk2rtz(float a, float b) {
    union { fp16x2 h; unsigned u; } x;
    x.h = __builtin_amdgcn_cvt_pkrtz(a, b);
    return x.u;
}
__device__ __forceinline__ uint2 pk4rtz(float a, float b, float c, float d) {
    return make_uint2(pk2rtz(a, b), pk2rtz(c, d));
}
__device__ __forceinline__ f16x8 frd(const unsigned short* p) {   // LDS, 8B-aligned
    union { struct { uint2 a, b; } u; f16x8 f; } x;
    x.u.a = *(const uint2*)p;
    x.u.b = *(const uint2*)(p + 4);
    return x.f;
}
__device__ __forceinline__ f16x8 gfrd(const unsigned short* p) {  // global, 16B-aligned
    union { uint4 u; f16x8 f; } x;
    x.u = *(const uint4*)p;
    return x.f;
}
__device__ __forceinline__ float2 upk2(unsigned u) {
    union { unsigned u; _Float16 h[2]; } x; x.u = u;
    return make_float2((float)x.h[0], (float)x.h[1]);
}

// ---- prep: fp16 weight planes [l][dout][din] + s2w^T f32 + zero gmax/cnt ----
extern "C" __global__ void idmpnn_prep(const float* __restrict__ w1,
                                       const float* __restrict__ w2,
                                       const float* __restrict__ s1w,
                                       const float* __restrict__ s2w,
                                       char* __restrict__ ws)
{
    unsigned short* wsu = (unsigned short*)ws;
    int idx = blockIdx.x * 256 + threadIdx.x;
    float v; int dst;
    if (idx < 16384) {
        int l = idx >> 12, r = idx & 4095, dp = r >> 6, e = r & 63;
        v = w1[l * 4096 + e * 64 + dp];
        dst = W1F + idx;
    } else if (idx < 32768) {
        int k = idx - 16384;
        int l = k >> 12, r = k & 4095, dp = r >> 6, e = r & 63;
        v = w2[l * 4096 + e * 64 + dp];
        dst = W2F + k;
    } else if (idx < 36864) {
        int k = idx - 32768, dp = k >> 6, e = k & 63;
        v = s1w[e * 64 + dp];
        dst = S1F + k;
    } else if (idx < 40960) {
        int k = idx - 36864, dp = k >> 6, e = k & 63;
        ((float*)(ws + S2WT_BYTE))[k] = s2w[e * 64 + dp];
        return;
    } else if (idx < 45056) {
        ((unsigned*)(ws + GMAX_BYTE))[idx - 40960] = 0u;
        return;
    } else if (idx < 45120) {
        ((unsigned*)(ws + CNT_BYTE))[idx - 45056] = 0u;
        return;
    } else return;
    union { _Float16 h; unsigned short u; } cv;
    cv.h = (_Float16)v;                 // RNE once
    wsu[dst] = cv.u;
}

extern "C" __global__ void __launch_bounds__(192, 3)
idmpnn_main(const int* __restrict__ xg, const float* __restrict__ subadj,
            const int* __restrict__ subgs, const int* __restrict__ num_node,
            const float* __restrict__ idemb, const float* __restrict__ node_emb,
            const float* __restrict__ b1g, const float* __restrict__ b2g,
            const float* __restrict__ lngm, const float* __restrict__ lnbm,
            const float* __restrict__ s1bm, const float* __restrict__ s2bm,
            const float* __restrict__ outw, const float* __restrict__ outb,
            const unsigned short* __restrict__ wsf, const float* __restrict__ s2wt,
            unsigned* __restrict__ gmax, unsigned* __restrict__ cnt,
            float* __restrict__ out)
{
    // 27648 + 768 + 4096 + 256 = 32768 B LDS -> 5 blocks/CU at 160KiB
    __shared__ unsigned short WB[6 * WBU];   // [perm] HB/GB views + final dump
    __shared__ float idS[KSUB * 64];
    __shared__ float prm[NLAYER * 4 * 64];   // b1,b2,g,be per layer
    __shared__ float HSf[HID];

    const int s = blockIdx.x, b = s >> 5;    // one subgraph per block
    const int tid = threadIdx.x;
    const int w = tid / 64, lane = tid & 63; // w = 0..2; wave owns perms 2w,2w+1
    const int c = lane & 15, q = lane >> 4;

    for (int t = tid; t < NLAYER * 4 * 64; t += 192) {
        int l = t >> 8, r2 = t & 255, set = r2 >> 6, d = r2 & 63;
        const float* src = (set == 0) ? b1g : (set == 1) ? b2g : (set == 2) ? lngm : lnbm;
        prm[t] = src[l * HID + d];
    }
    if (tid < KSUB * 64) idS[tid] = idemb[tid];

    const int nd0 = subgs[s * KSUB + 0];
    const int nd1 = subgs[s * KSUB + 1];
    const int nd2 = subgs[s * KSUB + 2];
    const int nn = num_node[b];
    const int zi0 = xg[b * NM + c];
    const int zi1 = xg[b * NM + 16 + c];

    // adjacency fp16 B-frags: lane holds adj[i=in*16+c][j=8q+jj], regs
    f16x8 adjf[2];
#pragma unroll
    for (int in_ = 0; in_ < 2; ++in_) {
        const float* ap = subadj + (size_t)b * NM * NM + (in_ * 16 + c) * NM + 8 * q;
        float4 f0 = *(const float4*)ap;
        float4 f1 = *(const float4*)(ap + 4);
        union { struct { uint2 a, b; } u; f16x8 f; } x;
        x.u.a = pk4rtz(f0.x, f0.y, f0.z, f0.w);
        x.u.b = pk4rtz(f1.x, f1.y, f1.z, f1.w);
        adjf[in_] = x.f;
    }

    __syncthreads();

    // chain ch (0,1) = perm w*2+ch; private buffer per chain
    unsigned short* wbc[2] = { WB + (w * 2 + 0) * WBU, WB + (w * 2 + 1) * WBU };

    // h packed 2xfp16: hpk[ch][in*8+dm*2+g2] = h[i=in*16+c][d=dm*16+4q+2g2+{0,1}]
    unsigned hpk[2][16];
#pragma unroll
    for (int in_ = 0; in_ < 2; ++in_) {
        int i = in_ * 16 + c;
        int z = in_ ? zi1 : zi0;
        int pid[2];
#pragma unroll
        for (int ch = 0; ch < 2; ++ch) {
            int p = w * 2 + ch;
            pid[ch] = (i == nd0) ? c_perm[0][p] : (i == nd1) ? c_perm[1][p]
                      : (i == nd2) ? c_perm[2][p] : -1;
        }
#pragma unroll
        for (int dm = 0; dm < 4; ++dm) {
            float4 e4 = *(const float4*)(node_emb + (size_t)z * HID + dm * 16 + 4 * q);
#pragma unroll
            for (int ch = 0; ch < 2; ++ch) {
                float4 v = e4;
                if (pid[ch] >= 0) {
                    float4 f4 = *(const float4*)&idS[pid[ch] * 64 + dm * 16 + 4 * q];
                    v.x *= f4.x; v.y *= f4.y; v.z *= f4.z; v.w *= f4.w;
                }
                uint2 u = pk4rtz(v.x, v.y, v.z, v.w);
                hpk[ch][in_ * 8 + dm * 2 + 0] = u.x;
                hpk[ch][in_ * 8 + dm * 2 + 1] = u.y;
            }
        }
    }

#pragma unroll 1
    for (int l = 0; l < NLAYER; ++l) {
        // (1) h -> HB [i][d], both chains
#pragma unroll
        for (int ch = 0; ch < 2; ++ch)
#pragma unroll
            for (int in_ = 0; in_ < 2; ++in_)
#pragma unroll
                for (int dm = 0; dm < 4; ++dm)
                    *(uint2*)(wbc[ch] + (in_ * 16 + c) * SH + dm * 16 + 4 * q) =
                        make_uint2(hpk[ch][in_ * 8 + dm * 2], hpk[ch][in_ * 8 + dm * 2 + 1]);

        // (2) GEMM-A A-frags, both chains
        f16x8 hah[2][2][2];
#pragma unroll
        for (int ch = 0; ch < 2; ++ch)
#pragma unroll
            for (int im = 0; im < 2; ++im)
#pragma unroll
                for (int ks = 0; ks < 2; ++ks)
                    hah[ch][im][ks] = frd(wbc[ch] + (im * 16 + c) * SH + ks * 32 + 8 * q);

        // (3+4) GEMM-A: g = h @ W1; write GB [d'][i] (weights shared)
#pragma unroll
        for (int jn = 0; jn < 4; ++jn) {
            const unsigned short* wp = wsf + W1F + (l * 64 + jn * 16 + c) * 64;
            f16x8 b0 = gfrd(wp + 8 * q);
            f16x8 b1 = gfrd(wp + 32 + 8 * q);
#pragma unroll
            for (int ch = 0; ch < 2; ++ch) {
                f32x4 g0 = {0.f, 0.f, 0.f, 0.f}, g1 = {0.f, 0.f, 0.f, 0.f};
                g0 = MFMA16(hah[ch][0][0], b0, g0);
                g0 = MFMA16(hah[ch][0][1], b1, g0);
                g1 = MFMA16(hah[ch][1][0], b0, g1);
                g1 = MFMA16(hah[ch][1][1], b1, g1);
                *(uint2*)(wbc[ch] + (jn * 16 + c) * SG + 4 * q)      = pk4rtz(g0[0], g0[1], g0[2], g0[3]);
                *(uint2*)(wbc[ch] + (jn * 16 + c) * SG + 16 + 4 * q) = pk4rtz(g1[0], g1[1], g1[2], g1[3]);
            }
        }

        // (5) GEMM-B A-frags
        f16x8 gah[2][4];
#pragma unroll
        for (int ch = 0; ch < 2; ++ch)
#pragma unroll
            for (int dm = 0; dm < 4; ++dm)
                gah[ch][dm] = frd(wbc[ch] + (dm * 16 + c) * SG + 8 * q);

        // (6+7) GEMM-B: t^T = g^T @ adjT; t -> HB with relu(+b1)
#pragma unroll
        for (int dm = 0; dm < 4; ++dm) {
            float4 b1v = *(const float4*)&prm[(l * 4 + 0) * 64 + dm * 16 + 4 * q];
#pragma unroll
            for (int ch = 0; ch < 2; ++ch) {
                f32x4 t0 = {0.f, 0.f, 0.f, 0.f}, t1 = {0.f, 0.f, 0.f, 0.f};
                t0 = MFMA16(gah[ch][dm], adjf[0], t0);
                t1 = MFMA16(gah[ch][dm], adjf[1], t1);
                *(uint2*)(wbc[ch] + c * SH + dm * 16 + 4 * q) =
                    pk4rtz(fmaxf(t0[0] + b1v.x, 0.f), fmaxf(t0[1] + b1v.y, 0.f),
                           fmaxf(t0[2] + b1v.z, 0.f), fmaxf(t0[3] + b1v.w, 0.f));
                *(uint2*)(wbc[ch] + (16 + c) * SH + dm * 16 + 4 * q) =
                    pk4rtz(fmaxf(t1[0] + b1v.x, 0.f), fmaxf(t1[1] + b1v.y, 0.f),
                           fmaxf(t1[2] + b1v.z, 0.f), fmaxf(t1[3] + b1v.w, 0.f));
            }
        }

        // (8) GEMM-C B-frags
        f16x8 tbh[2][2][2];
#pragma unroll
        for (int ch = 0; ch < 2; ++ch)
#pragma unroll
            for (int in_ = 0; in_ < 2; ++in_)
#pragma unroll
                for (int ks = 0; ks < 2; ++ks)
                    tbh[ch][in_][ks] = frd(wbc[ch] + (in_ * 16 + c) * SH + ks * 32 + 8 * q);

        // (9+10) GEMM-C': u^T = W2^T @ t^T; LN; relu; residual
#pragma unroll
        for (int in_ = 0; in_ < 2; ++in_) {
            float v[2][16];
            float s1[2] = {0.f, 0.f}, s2[2] = {0.f, 0.f};
#pragma unroll
            for (int dm = 0; dm < 4; ++dm) {
                const unsigned short* wp2 = wsf + W2F + (l * 64 + dm * 16 + c) * 64;
                f16x8 a0 = gfrd(wp2 + 8 * q);
                f16x8 a1 = gfrd(wp2 + 32 + 8 * q);
                float4 b2v = *(const float4*)&prm[(l * 4 + 1) * 64 + dm * 16 + 4 * q];
                const float* bb = (const float*)&b2v;
#pragma unroll
                for (int ch = 0; ch < 2; ++ch) {
                    f32x4 u = {0.f, 0.f, 0.f, 0.f};
                    u = MFMA16(a0, tbh[ch][in_][0], u);
                    u = MFMA16(a1, tbh[ch][in_][1], u);
#pragma unroll
                    for (int r = 0; r < 4; ++r) {
                        float x = u[r] + bb[r];
                        v[ch][dm * 4 + r] = x;
                        s1[ch] += x;
                        s2[ch] += x * x;
                    }
                }
            }
#pragma unroll
            for (int ch = 0; ch < 2; ++ch) {
                float a1 = s1[ch], a2 = s2[ch];
                a1 += __shfl_xor(a1, 16, 64); a1 += __shfl_xor(a1, 32, 64);
                a2 += __shfl_xor(a2, 16, 64); a2 += __shfl_xor(a2, 32, 64);
                float mean = a1 * (1.0f / HID);
                float var  = a2 * (1.0f / HID) - mean * mean;
                float rs   = rsqrtf(var + 1e-5f);
#pragma unroll
                for (int dm = 0; dm < 4; ++dm) {
                    float4 gv4  = *(const float4*)&prm[(l * 4 + 2) * 64 + dm * 16 + 4 * q];
                    float4 bev4 = *(const float4*)&prm[(l * 4 + 3) * 64 + dm * 16 + 4 * q];
                    const float* gp = (const float*)&gv4;
                    const float* bp = (const float*)&bev4;
                    float y0 = fmaxf((v[ch][dm * 4 + 0] - mean) * rs * gp[0] + bp[0], 0.f);
                    float y1 = fmaxf((v[ch][dm * 4 + 1] - mean) * rs * gp[1] + bp[1], 0.f);
                    float y2 = fmaxf((v[ch][dm * 4 + 2] - mean) * rs * gp[2] + bp[2], 0.f);
                    float y3 = fmaxf((v[ch][dm * 4 + 3] - mean) * rs * gp[3] + bp[3], 0.f);
                    int i0 = in_ * 8 + dm * 2;
                    float2 h0 = upk2(hpk[ch][i0 + 0]);
                    float2 h1 = upk2(hpk[ch][i0 + 1]);
                    hpk[ch][i0 + 0] = pk2rtz(h0.x + y0, h0.y + y1);
                    hpk[ch][i0 + 1] = pk2rtz(h1.x + y2, h1.y + y3);
                }
            }
        }
    }

    // ---- dump final h (fp16 [i][d]) into per-chain buffers ----
#pragma unroll
    for (int ch = 0; ch < 2; ++ch)
#pragma unroll
        for (int in_ = 0; in_ < 2; ++in_)
#pragma unroll
            for (int dm = 0; dm < 4; ++dm)
                *(uint2*)(wbc[ch] + (in_ * 16 + c) * SH + dm * 16 + 4 * q) =
                    make_uint2(hpk[ch][in_ * 8 + dm * 2], hpk[ch][in_ * 8 + dm * 2 + 1]);
    __syncthreads();

    // ---- tail (wave 0): combine 6 perms, GEMM-D, colsum, set2, pooling ----
    if (w == 0) {
        f16x8 mah[2][2];
#pragma unroll
        for (int im = 0; im < 2; ++im) {
            float sc = ((im * 16 + c) < nn) ? (1.0f / PP) : 0.f;
#pragma unroll
            for (int ks = 0; ks < 2; ++ks) {
                int ro = (im * 16 + c) * SH + ks * 32 + 8 * q;
                float acc8[8];
#pragma unroll
                for (int j = 0; j < 8; ++j) acc8[j] = 0.f;
#pragma unroll
                for (int pv = 0; pv < 6; ++pv) {
                    f16x8 f = frd(WB + pv * WBU + ro);
#pragma unroll
                    for (int j = 0; j < 8; ++j) acc8[j] += (float)f[j];
                }
                f16x8 m;
#pragma unroll
                for (int j = 0; j < 8; ++j) m[j] = (_Float16)(acc8[j] * sc);
                mah[im][ks] = m;
            }
        }

        // GEMM-D: h1 = hm @ set1_W (m=i, n=dout)
        f32x4 hh[2][4];
#pragma unroll
        for (int im = 0; im < 2; ++im)
#pragma unroll
            for (int jn = 0; jn < 4; ++jn) hh[im][jn] = (f32x4){0.f, 0.f, 0.f, 0.f};
#pragma unroll
        for (int jn = 0; jn < 4; ++jn) {
            const unsigned short* sp = wsf + S1F + (jn * 16 + c) * 64;
            f16x8 b0 = gfrd(sp + 8 * q);
            f16x8 b1 = gfrd(sp + 32 + 8 * q);
#pragma unroll
            for (int im = 0; im < 2; ++im) {
                hh[im][jn] = MFMA16(mah[im][0], b0, hh[im][jn]);
                hh[im][jn] = MFMA16(mah[im][1], b1, hh[im][jn]);
            }
        }
        // colsum over all 32 rows (padded rows contribute relu(s1b), as ref)
#pragma unroll
        for (int jn = 0; jn < 4; ++jn) {
            float sb = s1bm[jn * 16 + c];
            float cs = 0.f;
#pragma unroll
            for (int im = 0; im < 2; ++im)
#pragma unroll
                for (int r = 0; r < 4; ++r)
                    cs += fmaxf(hh[im][jn][r] + sb, 0.f);
            cs += __shfl_xor(cs, 16, 64);
            cs += __shfl_xor(cs, 32, 64);
            if (q == 0) HSf[jn * 16 + c] = cs;
        }

        // h2 = relu(HS @ set2_W + s2b), lane = dout
        float acc = 0.f;
#pragma unroll
        for (int e4 = 0; e4 < 16; ++e4) {
            float4 wv = *(const float4*)&s2wt[lane * 64 + e4 * 4];
            float4 hv = *(const float4*)&HSf[e4 * 4];
            acc += hv.x * wv.x + hv.y * wv.y + hv.z * wv.z + hv.w * wv.w;
        }
        float h2 = fmaxf(acc + s2bm[lane], 0.f);

        // pooling fold: device-scope atomicMax (h2 >= 0: uint order == float order)
        atomicMax(&gmax[b * HID + lane], __float_as_uint(h2));
        __threadfence();
        unsigned old = 0;
        if (lane == 0) old = atomicAdd(&cnt[b], 1u);
        old = __shfl(old, 0, 64);
        if (old == NS - 1) {   // last of the 32 subgraph-writers of this graph
            __threadfence();
            unsigned mbits = atomicOr(&gmax[b * HID + lane], 0u);
            float v = __uint_as_float(mbits) * outw[lane];
#pragma unroll
            for (int off = 32; off > 0; off >>= 1) v += __shfl_xor(v, off, 64);
            if (lane == 0) out[b] = v + outb[0];
        }
    }
}

extern "C" void kernel_launch(void* const* d_in, const int* in_sizes, int n_in,
                              void* d_out, int out_size, void* d_ws, size_t ws_size,
                              hipStream_t stream)
{
    const int*   xg       = (const int*)d_in[0];
    const float* subadj   = (const float*)d_in[1];
    const int*   subgs    = (const int*)d_in[2];
    const int*   num_node = (const int*)d_in[3];
    const float* idemb    = (const float*)d_in[5];
    const float* node_emb = (const float*)d_in[6];
    const float* w1       = (const float*)d_in[7];
    const float* b1       = (const float*)d_in[8];
    const float* w2       = (const float*)d_in[9];
    const float* b2       = (const float*)d_in[10];
    const float* g        = (const float*)d_in[11];
    const float* be       = (const float*)d_in[12];
    const float* s1w      = (const float*)d_in[13];
    const float* s1b      = (const float*)d_in[14];
    const float* s2w      = (const float*)d_in[15];
    const float* s2b      = (const float*)d_in[16];
    const float* outw     = (const float*)d_in[17];
    const float* outb     = (const float*)d_in[18];

    char* ws = (char*)d_ws;
    unsigned short* wsf = (unsigned short*)ws;
    const float* s2wt = (const float*)(ws + S2WT_BYTE);
    unsigned* gmax = (unsigned*)(ws + GMAX_BYTE);
    unsigned* cnt  = (unsigned*)(ws + CNT_BYTE);

    idmpnn_prep<<<177, 256, 0, stream>>>(w1, w2, s1w, s2w, ws);
    idmpnn_main<<<STOT, 192, 0, stream>>>(xg, subadj, subgs, num_node,
                                          idemb, node_emb,
                                          b1, b2, g, be, s1b, s2b, outw, outb,
                                          wsf, s2wt, gmax, cnt, (float*)d_out);
}

// Round 12
// 203.117 us; speedup vs baseline: 1.1822x; 1.1489x over previous
//
#include <hip/hip_runtime.h>
#include <math.h>

// IDMPNN fused forward — R12: R11 with __launch_bounds__(192,2).
// R11 repeated the R4/R6 trap: (192,3) squeezed the allocator to 84 arch VGPRs,
// spilling the 2-chain state (WRITE_SIZE 0.58->80MB). This kernel needs ~128
// arch VGPRs; min-waves bound must stay at 2. With ~128 VGPR: 4 waves/SIMD
// possible, 3-wave blocks + 32KB LDS -> 5 blocks/CU = 15 waves = 30 chains/CU
// (R9 managed 12 waves/24 chains at 139us). Math bit-identical to R9/R11.

#define NBATCH 64
#define NM 32
#define NS 32
#define KSUB 3
#define HID 64
#define NLAYER 4
#define PP 6
#define STOT (NBATCH * NS)

// d_ws: fp16 weight planes (ushort offsets), then byte offsets
#define W1F 0            // [l][dout][din] 16384
#define W2F 16384
#define S1F 32768        // planes end at ushort 36864 = byte 73728
#define GMAX_BYTE 73728  // uint[64*64]
#define CNT_BYTE  90112  // uint[64]
#define S2WT_BYTE 90368  // float[64*64]

// LDS row strides (ushorts)
#define SH 68    // HB rows (32 x 64 fp16 + pad)
#define SG 36    // GB rows (64 x 32 fp16 + pad)
#define WBU 2304 // per-chain buffer ushorts (4608B): max(32*68, 64*36)

typedef _Float16 f16x8 __attribute__((ext_vector_type(8)));
typedef __fp16 fp16x2 __attribute__((ext_vector_type(2)));   // cvt_pkrtz return
typedef float f32x4 __attribute__((ext_vector_type(4)));

#define MFMA16(a, b, c) __builtin_amdgcn_mfma_f32_16x16x32_f16(a, b, c, 0, 0, 0)

__constant__ int c_perm[KSUB][PP] = {
    {0, 0, 1, 1, 2, 2},
    {1, 2, 0, 2, 0, 1},
    {2, 1, 2, 0, 1, 0}
};

__device__ __forceinline__ unsigned pk2rtz(float a, float b) {
    union { fp16x2 h; unsigned u; } x;
    x.h = __builtin_amdgcn_cvt_pkrtz(a, b);
    return x.u;
}
__device__ __forceinline__ uint2 pk4rtz(float a, float b, float c, float d) {
    return make_uint2(pk2rtz(a, b), pk2rtz(c, d));
}
__device__ __forceinline__ f16x8 frd(const unsigned short* p) {   // LDS, 8B-aligned
    union { struct { uint2 a, b; } u; f16x8 f; } x;
    x.u.a = *(const uint2*)p;
    x.u.b = *(const uint2*)(p + 4);
    return x.f;
}
__device__ __forceinline__ f16x8 gfrd(const unsigned short* p) {  // global, 16B-aligned
    union { uint4 u; f16x8 f; } x;
    x.u = *(const uint4*)p;
    return x.f;
}
__device__ __forceinline__ float2 upk2(unsigned u) {
    union { unsigned u; _Float16 h[2]; } x; x.u = u;
    return make_float2((float)x.h[0], (float)x.h[1]);
}

// ---- prep: fp16 weight planes [l][dout][din] + s2w^T f32 + zero gmax/cnt ----
extern "C" __global__ void idmpnn_prep(const float* __restrict__ w1,
                                       const float* __restrict__ w2,
                                       const float* __restrict__ s1w,
                                       const float* __restrict__ s2w,
                                       char* __restrict__ ws)
{
    unsigned short* wsu = (unsigned short*)ws;
    int idx = blockIdx.x * 256 + threadIdx.x;
    float v; int dst;
    if (idx < 16384) {
        int l = idx >> 12, r = idx & 4095, dp = r >> 6, e = r & 63;
        v = w1[l * 4096 + e * 64 + dp];
        dst = W1F + idx;
    } else if (idx < 32768) {
        int k = idx - 16384;
        int l = k >> 12, r = k & 4095, dp = r >> 6, e = r & 63;
        v = w2[l * 4096 + e * 64 + dp];
        dst = W2F + k;
    } else if (idx < 36864) {
        int k = idx - 32768, dp = k >> 6, e = k & 63;
        v = s1w[e * 64 + dp];
        dst = S1F + k;
    } else if (idx < 40960) {
        int k = idx - 36864, dp = k >> 6, e = k & 63;
        ((float*)(ws + S2WT_BYTE))[k] = s2w[e * 64 + dp];
        return;
    } else if (idx < 45056) {
        ((unsigned*)(ws + GMAX_BYTE))[idx - 40960] = 0u;
        return;
    } else if (idx < 45120) {
        ((unsigned*)(ws + CNT_BYTE))[idx - 45056] = 0u;
        return;
    } else return;
    union { _Float16 h; unsigned short u; } cv;
    cv.h = (_Float16)v;                 // RNE once
    wsu[dst] = cv.u;
}

extern "C" __global__ void __launch_bounds__(192, 2)
idmpnn_main(const int* __restrict__ xg, const float* __restrict__ subadj,
            const int* __restrict__ subgs, const int* __restrict__ num_node,
            const float* __restrict__ idemb, const float* __restrict__ node_emb,
            const float* __restrict__ b1g, const float* __restrict__ b2g,
            const float* __restrict__ lngm, const float* __restrict__ lnbm,
            const float* __restrict__ s1bm, const float* __restrict__ s2bm,
            const float* __restrict__ outw, const float* __restrict__ outb,
            const unsigned short* __restrict__ wsf, const float* __restrict__ s2wt,
            unsigned* __restrict__ gmax, unsigned* __restrict__ cnt,
            float* __restrict__ out)
{
    // 27648 + 768 + 4096 + 256 = 32768 B LDS -> 5 blocks/CU at 160KiB
    __shared__ unsigned short WB[6 * WBU];   // [perm] HB/GB views + final dump
    __shared__ float idS[KSUB * 64];
    __shared__ float prm[NLAYER * 4 * 64];   // b1,b2,g,be per layer
    __shared__ float HSf[HID];

    const int s = blockIdx.x, b = s >> 5;    // one subgraph per block
    const int tid = threadIdx.x;
    const int w = tid / 64, lane = tid & 63; // w = 0..2; wave owns perms 2w,2w+1
    const int c = lane & 15, q = lane >> 4;

    for (int t = tid; t < NLAYER * 4 * 64; t += 192) {
        int l = t >> 8, r2 = t & 255, set = r2 >> 6, d = r2 & 63;
        const float* src = (set == 0) ? b1g : (set == 1) ? b2g : (set == 2) ? lngm : lnbm;
        prm[t] = src[l * HID + d];
    }
    if (tid < KSUB * 64) idS[tid] = idemb[tid];

    const int nd0 = subgs[s * KSUB + 0];
    const int nd1 = subgs[s * KSUB + 1];
    const int nd2 = subgs[s * KSUB + 2];
    const int nn = num_node[b];
    const int zi0 = xg[b * NM + c];
    const int zi1 = xg[b * NM + 16 + c];

    // adjacency fp16 B-frags: lane holds adj[i=in*16+c][j=8q+jj], regs
    f16x8 adjf[2];
#pragma unroll
    for (int in_ = 0; in_ < 2; ++in_) {
        const float* ap = subadj + (size_t)b * NM * NM + (in_ * 16 + c) * NM + 8 * q;
        float4 f0 = *(const float4*)ap;
        float4 f1 = *(const float4*)(ap + 4);
        union { struct { uint2 a, b; } u; f16x8 f; } x;
        x.u.a = pk4rtz(f0.x, f0.y, f0.z, f0.w);
        x.u.b = pk4rtz(f1.x, f1.y, f1.z, f1.w);
        adjf[in_] = x.f;
    }

    __syncthreads();

    // chain ch (0,1) = perm w*2+ch; private buffer per chain
    unsigned short* wbc[2] = { WB + (w * 2 + 0) * WBU, WB + (w * 2 + 1) * WBU };

    // h packed 2xfp16: hpk[ch][in*8+dm*2+g2] = h[i=in*16+c][d=dm*16+4q+2g2+{0,1}]
    unsigned hpk[2][16];
#pragma unroll
    for (int in_ = 0; in_ < 2; ++in_) {
        int i = in_ * 16 + c;
        int z = in_ ? zi1 : zi0;
        int pid[2];
#pragma unroll
        for (int ch = 0; ch < 2; ++ch) {
            int p = w * 2 + ch;
            pid[ch] = (i == nd0) ? c_perm[0][p] : (i == nd1) ? c_perm[1][p]
                      : (i == nd2) ? c_perm[2][p] : -1;
        }
#pragma unroll
        for (int dm = 0; dm < 4; ++dm) {
            float4 e4 = *(const float4*)(node_emb + (size_t)z * HID + dm * 16 + 4 * q);
#pragma unroll
            for (int ch = 0; ch < 2; ++ch) {
                float4 v = e4;
                if (pid[ch] >= 0) {
                    float4 f4 = *(const float4*)&idS[pid[ch] * 64 + dm * 16 + 4 * q];
                    v.x *= f4.x; v.y *= f4.y; v.z *= f4.z; v.w *= f4.w;
                }
                uint2 u = pk4rtz(v.x, v.y, v.z, v.w);
                hpk[ch][in_ * 8 + dm * 2 + 0] = u.x;
                hpk[ch][in_ * 8 + dm * 2 + 1] = u.y;
            }
        }
    }

#pragma unroll 1
    for (int l = 0; l < NLAYER; ++l) {
        // (1) h -> HB [i][d], both chains
#pragma unroll
        for (int ch = 0; ch < 2; ++ch)
#pragma unroll
            for (int in_ = 0; in_ < 2; ++in_)
#pragma unroll
                for (int dm = 0; dm < 4; ++dm)
                    *(uint2*)(wbc[ch] + (in_ * 16 + c) * SH + dm * 16 + 4 * q) =
                        make_uint2(hpk[ch][in_ * 8 + dm * 2], hpk[ch][in_ * 8 + dm * 2 + 1]);

        // (2) GEMM-A A-frags, both chains
        f16x8 hah[2][2][2];
#pragma unroll
        for (int ch = 0; ch < 2; ++ch)
#pragma unroll
            for (int im = 0; im < 2; ++im)
#pragma unroll
                for (int ks = 0; ks < 2; ++ks)
                    hah[ch][im][ks] = frd(wbc[ch] + (im * 16 + c) * SH + ks * 32 + 8 * q);

        // (3+4) GEMM-A: g = h @ W1; write GB [d'][i] (weights shared)
#pragma unroll
        for (int jn = 0; jn < 4; ++jn) {
            const unsigned short* wp = wsf + W1F + (l * 64 + jn * 16 + c) * 64;
            f16x8 b0 = gfrd(wp + 8 * q);
            f16x8 b1 = gfrd(wp + 32 + 8 * q);
#pragma unroll
            for (int ch = 0; ch < 2; ++ch) {
                f32x4 g0 = {0.f, 0.f, 0.f, 0.f}, g1 = {0.f, 0.f, 0.f, 0.f};
                g0 = MFMA16(hah[ch][0][0], b0, g0);
                g0 = MFMA16(hah[ch][0][1], b1, g0);
                g1 = MFMA16(hah[ch][1][0], b0, g1);
                g1 = MFMA16(hah[ch][1][1], b1, g1);
                *(uint2*)(wbc[ch] + (jn * 16 + c) * SG + 4 * q)      = pk4rtz(g0[0], g0[1], g0[2], g0[3]);
                *(uint2*)(wbc[ch] + (jn * 16 + c) * SG + 16 + 4 * q) = pk4rtz(g1[0], g1[1], g1[2], g1[3]);
            }
        }

        // (5) GEMM-B A-frags
        f16x8 gah[2][4];
#pragma unroll
        for (int ch = 0; ch < 2; ++ch)
#pragma unroll
            for (int dm = 0; dm < 4; ++dm)
                gah[ch][dm] = frd(wbc[ch] + (dm * 16 + c) * SG + 8 * q);

        // (6+7) GEMM-B: t^T = g^T @ adjT; t -> HB with relu(+b1)
#pragma unroll
        for (int dm = 0; dm < 4; ++dm) {
            float4 b1v = *(const float4*)&prm[(l * 4 + 0) * 64 + dm * 16 + 4 * q];
#pragma unroll
            for (int ch = 0; ch < 2; ++ch) {
                f32x4 t0 = {0.f, 0.f, 0.f, 0.f}, t1 = {0.f, 0.f, 0.f, 0.f};
                t0 = MFMA16(gah[ch][dm], adjf[0], t0);
                t1 = MFMA16(gah[ch][dm], adjf[1], t1);
                *(uint2*)(wbc[ch] + c * SH + dm * 16 + 4 * q) =
                    pk4rtz(fmaxf(t0[0] + b1v.x, 0.f), fmaxf(t0[1] + b1v.y, 0.f),
                           fmaxf(t0[2] + b1v.z, 0.f), fmaxf(t0[3] + b1v.w, 0.f));
                *(uint2*)(wbc[ch] + (16 + c) * SH + dm * 16 + 4 * q) =
                    pk4rtz(fmaxf(t1[0] + b1v.x, 0.f), fmaxf(t1[1] + b1v.y, 0.f),
                           fmaxf(t1[2] + b1v.z, 0.f), fmaxf(t1[3] + b1v.w, 0.f));
            }
        }

        // (8) GEMM-C B-frags
        f16x8 tbh[2][2][2];
#pragma unroll
        for (int ch = 0; ch < 2; ++ch)
#pragma unroll
            for (int in_ = 0; in_ < 2; ++in_)
#pragma unroll
                for (int ks = 0; ks < 2; ++ks)
                    tbh[ch][in_][ks] = frd(wbc[ch] + (in_ * 16 + c) * SH + ks * 32 + 8 * q);

        // (9+10) GEMM-C': u^T = W2^T @ t^T; LN; relu; residual
#pragma unroll
        for (int in_ = 0; in_ < 2; ++in_) {
            float v[2][16];
            float s1[2] = {0.f, 0.f}, s2[2] = {0.f, 0.f};
#pragma unroll
            for (int dm = 0; dm < 4; ++dm) {
                const unsigned short* wp2 = wsf + W2F + (l * 64 + dm * 16 + c) * 64;
                f16x8 a0 = gfrd(wp2 + 8 * q);
                f16x8 a1 = gfrd(wp2 + 32 + 8 * q);
                float4 b2v = *(const float4*)&prm[(l * 4 + 1) * 64 + dm * 16 + 4 * q];
                const float* bb = (const float*)&b2v;
#pragma unroll
                for (int ch = 0; ch < 2; ++ch) {
                    f32x4 u = {0.f, 0.f, 0.f, 0.f};
                    u = MFMA16(a0, tbh[ch][in_][0], u);
                    u = MFMA16(a1, tbh[ch][in_][1], u);
#pragma unroll
                    for (int r = 0; r < 4; ++r) {
                        float x = u[r] + bb[r];
                        v[ch][dm * 4 + r] = x;
                        s1[ch] += x;
                        s2[ch] += x * x;
                    }
                }
            }
#pragma unroll
            for (int ch = 0; ch < 2; ++ch) {
                float a1 = s1[ch], a2 = s2[ch];
                a1 += __shfl_xor(a1, 16, 64); a1 += __shfl_xor(a1, 32, 64);
                a2 += __shfl_xor(a2, 16, 64); a2 += __shfl_xor(a2, 32, 64);
                float mean = a1 * (1.0f / HID);
                float var  = a2 * (1.0f / HID) - mean * mean;
                float rs   = rsqrtf(var + 1e-5f);
#pragma unroll
                for (int dm = 0; dm < 4; ++dm) {
                    float4 gv4  = *(const float4*)&prm[(l * 4 + 2) * 64 + dm * 16 + 4 * q];
                    float4 bev4 = *(const float4*)&prm[(l * 4 + 3) * 64 + dm * 16 + 4 * q];
                    const float* gp = (const float*)&gv4;
                    const float* bp = (const float*)&bev4;
                    float y0 = fmaxf((v[ch][dm * 4 + 0] - mean) * rs * gp[0] + bp[0], 0.f);
                    float y1 = fmaxf((v[ch][dm * 4 + 1] - mean) * rs * gp[1] + bp[1], 0.f);
                    float y2 = fmaxf((v[ch][dm * 4 + 2] - mean) * rs * gp[2] + bp[2], 0.f);
                    float y3 = fmaxf((v[ch][dm * 4 + 3] - mean) * rs * gp[3] + bp[3], 0.f);
                    int i0 = in_ * 8 + dm * 2;
                    float2 h0 = upk2(hpk[ch][i0 + 0]);
                    float2 h1 = upk2(hpk[ch][i0 + 1]);
                    hpk[ch][i0 + 0] = pk2rtz(h0.x + y0, h0.y + y1);
                    hpk[ch][i0 + 1] = pk2rtz(h1.x + y2, h1.y + y3);
                }
            }
        }
    }

    // ---- dump final h (fp16 [i][d]) into per-chain buffers ----
#pragma unroll
    for (int ch = 0; ch < 2; ++ch)
#pragma unroll
        for (int in_ = 0; in_ < 2; ++in_)
#pragma unroll
            for (int dm = 0; dm < 4; ++dm)
                *(uint2*)(wbc[ch] + (in_ * 16 + c) * SH + dm * 16 + 4 * q) =
                    make_uint2(hpk[ch][in_ * 8 + dm * 2], hpk[ch][in_ * 8 + dm * 2 + 1]);
    __syncthreads();

    // ---- tail (wave 0): combine 6 perms, GEMM-D, colsum, set2, pooling ----
    if (w == 0) {
        f16x8 mah[2][2];
#pragma unroll
        for (int im = 0; im < 2; ++im) {
            float sc = ((im * 16 + c) < nn) ? (1.0f / PP) : 0.f;
#pragma unroll
            for (int ks = 0; ks < 2; ++ks) {
                int ro = (im * 16 + c) * SH + ks * 32 + 8 * q;
                float acc8[8];
#pragma unroll
                for (int j = 0; j < 8; ++j) acc8[j] = 0.f;
#pragma unroll
                for (int pv = 0; pv < 6; ++pv) {
                    f16x8 f = frd(WB + pv * WBU + ro);
#pragma unroll
                    for (int j = 0; j < 8; ++j) acc8[j] += (float)f[j];
                }
                f16x8 m;
#pragma unroll
                for (int j = 0; j < 8; ++j) m[j] = (_Float16)(acc8[j] * sc);
                mah[im][ks] = m;
            }
        }

        // GEMM-D: h1 = hm @ set1_W (m=i, n=dout)
        f32x4 hh[2][4];
#pragma unroll
        for (int im = 0; im < 2; ++im)
#pragma unroll
            for (int jn = 0; jn < 4; ++jn) hh[im][jn] = (f32x4){0.f, 0.f, 0.f, 0.f};
#pragma unroll
        for (int jn = 0; jn < 4; ++jn) {
            const unsigned short* sp = wsf + S1F + (jn * 16 + c) * 64;
            f16x8 b0 = gfrd(sp + 8 * q);
            f16x8 b1 = gfrd(sp + 32 + 8 * q);
#pragma unroll
            for (int im = 0; im < 2; ++im) {
                hh[im][jn] = MFMA16(mah[im][0], b0, hh[im][jn]);
                hh[im][jn] = MFMA16(mah[im][1], b1, hh[im][jn]);
            }
        }
        // colsum over all 32 rows (padded rows contribute relu(s1b), as ref)
#pragma unroll
        for (int jn = 0; jn < 4; ++jn) {
            float sb = s1bm[jn * 16 + c];
            float cs = 0.f;
#pragma unroll
            for (int im = 0; im < 2; ++im)
#pragma unroll
                for (int r = 0; r < 4; ++r)
                    cs += fmaxf(hh[im][jn][r] + sb, 0.f);
            cs += __shfl_xor(cs, 16, 64);
            cs += __shfl_xor(cs, 32, 64);
            if (q == 0) HSf[jn * 16 + c] = cs;
        }

        // h2 = relu(HS @ set2_W + s2b), lane = dout
        float acc = 0.f;
#pragma unroll
        for (int e4 = 0; e4 < 16; ++e4) {
            float4 wv = *(const float4*)&s2wt[lane * 64 + e4 * 4];
            float4 hv = *(const float4*)&HSf[e4 * 4];
            acc += hv.x * wv.x + hv.y * wv.y + hv.z * wv.z + hv.w * wv.w;
        }
        float h2 = fmaxf(acc + s2bm[lane], 0.f);

        // pooling fold: device-scope atomicMax (h2 >= 0: uint order == float order)
        atomicMax(&gmax[b * HID + lane], __float_as_uint(h2));
        __threadfence();
        unsigned old = 0;
        if (lane == 0) old = atomicAdd(&cnt[b], 1u);
        old = __shfl(old, 0, 64);
        if (old == NS - 1) {   // last of the 32 subgraph-writers of this graph
            __threadfence();
            unsigned mbits = atomicOr(&gmax[b * HID + lane], 0u);
            float v = __uint_as_float(mbits) * outw[lane];
#pragma unroll
            for (int off = 32; off > 0; off >>= 1) v += __shfl_xor(v, off, 64);
            if (lane == 0) out[b] = v + outb[0];
        }
    }
}

extern "C" void kernel_launch(void* const* d_in, const int* in_sizes, int n_in,
                              void* d_out, int out_size, void* d_ws, size_t ws_size,
                              hipStream_t stream)
{
    const int*   xg       = (const int*)d_in[0];
    const float* subadj   = (const float*)d_in[1];
    const int*   subgs    = (const int*)d_in[2];
    const int*   num_node = (const int*)d_in[3];
    const float* idemb    = (const float*)d_in[5];
    const float* node_emb = (const float*)d_in[6];
    const float* w1       = (const float*)d_in[7];
    const float* b1       = (const float*)d_in[8];
    const float* w2       = (const float*)d_in[9];
    const float* b2       = (const float*)d_in[10];
    const float* g        = (const float*)d_in[11];
    const float* be       = (const float*)d_in[12];
    const float* s1w      = (const float*)d_in[13];
    const float* s1b      = (const float*)d_in[14];
    const float* s2w      = (const float*)d_in[15];
    const float* s2b      = (const float*)d_in[16];
    const float* outw     = (const float*)d_in[17];
    const float* outb     = (const float*)d_in[18];

    char* ws = (char*)d_ws;
    unsigned short* wsf = (unsigned short*)ws;
    const float* s2wt = (const float*)(ws + S2WT_BYTE);
    unsigned* gmax = (unsigned*)(ws + GMAX_BYTE);
    unsigned* cnt  = (unsigned*)(ws + CNT_BYTE);

    idmpnn_prep<<<177, 256, 0, stream>>>(w1, w2, s1w, s2w, ws);
    idmpnn_main<<<STOT, 192, 0, stream>>>(xg, subadj, subgs, num_node,
                                          idemb, node_emb,
                                          b1, b2, g, be, s1b, s2b, outw, outb,
                                          wsf, s2wt, gmax, cnt, (float*)d_out);
}

// Round 13
// 199.747 us; speedup vs baseline: 1.2022x; 1.0169x over previous
//
#include <hip/hip_runtime.h>
#include <math.h>

// IDMPNN fused forward — R13: R12 main (125us, best) UNCHANGED + prep rewritten
// as coalesced LDS tile transpose. Old prep read w[e*64+dp] with e varying per
// lane -> 256B stride, 64 lines/wave-load, ~37k serialized L2 transactions ->
// suspected ~60-70us of the constant 78us bench-vs-main gap. New prep: 12
// blocks, each does one 64x64 tile: coalesced read -> float[64][65] LDS ->
// coalesced fp16 write. Same values, same layout, same RNE conversion.

#define NBATCH 64
#define NM 32
#define NS 32
#define KSUB 3
#define HID 64
#define NLAYER 4
#define PP 6
#define STOT (NBATCH * NS)

// d_ws: fp16 weight planes (ushort offsets), then byte offsets
#define W1F 0            // [l][dout][din] 16384
#define W2F 16384
#define S1F 32768        // planes end at ushort 36864 = byte 73728
#define GMAX_BYTE 73728  // uint[64*64]
#define CNT_BYTE  90112  // uint[64]
#define S2WT_BYTE 90368  // float[64*64]

// LDS row strides (ushorts)
#define SH 68    // HB rows (32 x 64 fp16 + pad)
#define SG 36    // GB rows (64 x 32 fp16 + pad)
#define WBU 2304 // per-chain buffer ushorts (4608B): max(32*68, 64*36)

typedef _Float16 f16x8 __attribute__((ext_vector_type(8)));
typedef __fp16 fp16x2 __attribute__((ext_vector_type(2)));   // cvt_pkrtz return
typedef float f32x4 __attribute__((ext_vector_type(4)));

#define MFMA16(a, b, c) __builtin_amdgcn_mfma_f32_16x16x32_f16(a, b, c, 0, 0, 0)

__constant__ int c_perm[KSUB][PP] = {
    {0, 0, 1, 1, 2, 2},
    {1, 2, 0, 2, 0, 1},
    {2, 1, 2, 0, 1, 0}
};

__device__ __forceinline__ unsigned pk2rtz(float a, float b) {
    union { fp16x2 h; unsigned u; } x;
    x.h = __builtin_amdgcn_cvt_pkrtz(a, b);
    return x.u;
}
__device__ __forceinline__ uint2 pk4rtz(float a, float b, float c, float d) {
    return make_uint2(pk2rtz(a, b), pk2rtz(c, d));
}
__device__ __forceinline__ f16x8 frd(const unsigned short* p) {   // LDS, 8B-aligned
    union { struct { uint2 a, b; } u; f16x8 f; } x;
    x.u.a = *(const uint2*)p;
    x.u.b = *(const uint2*)(p + 4);
    return x.f;
}
__device__ __forceinline__ f16x8 gfrd(const unsigned short* p) {  // global, 16B-aligned
    union { uint4 u; f16x8 f; } x;
    x.u = *(const uint4*)p;
    return x.f;
}
__device__ __forceinline__ float2 upk2(unsigned u) {
    union { unsigned u; _Float16 h[2]; } x; x.u = u;
    return make_float2((float)x.h[0], (float)x.h[1]);
}

// ---- prep v2: coalesced LDS tile transpose ----
// blocks 0-3: W1[l] -> [dout][din] fp16; 4-7: W2[l]; 8: set1_W; 9: s2w^T f32;
// 10: zero gmax; 11: zero cnt. Each transpose block: coalesced read ->
// tile[c][r] (stride-65 kills bank conflicts) -> coalesced write.
extern "C" __global__ void idmpnn_prep(const float* __restrict__ w1,
                                       const float* __restrict__ w2,
                                       const float* __restrict__ s1w,
                                       const float* __restrict__ s2w,
                                       char* __restrict__ ws)
{
    __shared__ float tile[64][65];
    unsigned short* wsu = (unsigned short*)ws;
    const int bid = blockIdx.x, t = threadIdx.x;   // 256 threads

    if (bid < 9) {
        const float* src;
        unsigned short* dst;
        if (bid < 4)      { src = w1 + bid * 4096;       dst = wsu + W1F + bid * 4096; }
        else if (bid < 8) { src = w2 + (bid - 4) * 4096; dst = wsu + W2F + (bid - 4) * 4096; }
        else              { src = s1w;                   dst = wsu + S1F; }
#pragma unroll
        for (int k = 0; k < 16; ++k) {
            int lin = k * 256 + t;                 // coalesced read
            tile[lin & 63][lin >> 6] = src[lin];   // tile[c][r] = src[r][c]
        }
        __syncthreads();
#pragma unroll
        for (int k = 0; k < 16; ++k) {
            int lin = k * 256 + t;                 // coalesced write
            union { _Float16 h; unsigned short u; } cv;
            cv.h = (_Float16)tile[lin >> 6][lin & 63];  // RNE, same as before
            dst[lin] = cv.u;
        }
    } else if (bid == 9) {
        float* dstf = (float*)(ws + S2WT_BYTE);
#pragma unroll
        for (int k = 0; k < 16; ++k) {
            int lin = k * 256 + t;
            tile[lin & 63][lin >> 6] = s2w[lin];
        }
        __syncthreads();
#pragma unroll
        for (int k = 0; k < 16; ++k) {
            int lin = k * 256 + t;
            dstf[lin] = tile[lin >> 6][lin & 63];
        }
    } else if (bid == 10) {
        unsigned* g = (unsigned*)(ws + GMAX_BYTE);
#pragma unroll
        for (int k = 0; k < 16; ++k) g[k * 256 + t] = 0u;
    } else {
        if (t < 64) ((unsigned*)(ws + CNT_BYTE))[t] = 0u;
    }
}

extern "C" __global__ void __launch_bounds__(192, 2)
idmpnn_main(const int* __restrict__ xg, const float* __restrict__ subadj,
            const int* __restrict__ subgs, const int* __restrict__ num_node,
            const float* __restrict__ idemb, const float* __restrict__ node_emb,
            const float* __restrict__ b1g, const float* __restrict__ b2g,
            const float* __restrict__ lngm, const float* __restrict__ lnbm,
            const float* __restrict__ s1bm, const float* __restrict__ s2bm,
            const float* __restrict__ outw, const float* __restrict__ outb,
            const unsigned short* __restrict__ wsf, const float* __restrict__ s2wt,
            unsigned* __restrict__ gmax, unsigned* __restrict__ cnt,
            float* __restrict__ out)
{
    // 27648 + 768 + 4096 + 256 = 32768 B LDS
    __shared__ unsigned short WB[6 * WBU];   // [perm] HB/GB views + final dump
    __shared__ float idS[KSUB * 64];
    __shared__ float prm[NLAYER * 4 * 64];   // b1,b2,g,be per layer
    __shared__ float HSf[HID];

    const int s = blockIdx.x, b = s >> 5;    // one subgraph per block
    const int tid = threadIdx.x;
    const int w = tid / 64, lane = tid & 63; // w = 0..2; wave owns perms 2w,2w+1
    const int c = lane & 15, q = lane >> 4;

    for (int t = tid; t < NLAYER * 4 * 64; t += 192) {
        int l = t >> 8, r2 = t & 255, set = r2 >> 6, d = r2 & 63;
        const float* src = (set == 0) ? b1g : (set == 1) ? b2g : (set == 2) ? lngm : lnbm;
        prm[t] = src[l * HID + d];
    }
    if (tid < KSUB * 64) idS[tid] = idemb[tid];

    const int nd0 = subgs[s * KSUB + 0];
    const int nd1 = subgs[s * KSUB + 1];
    const int nd2 = subgs[s * KSUB + 2];
    const int nn = num_node[b];
    const int zi0 = xg[b * NM + c];
    const int zi1 = xg[b * NM + 16 + c];

    // adjacency fp16 B-frags: lane holds adj[i=in*16+c][j=8q+jj], regs
    f16x8 adjf[2];
#pragma unroll
    for (int in_ = 0; in_ < 2; ++in_) {
        const float* ap = subadj + (size_t)b * NM * NM + (in_ * 16 + c) * NM + 8 * q;
        float4 f0 = *(const float4*)ap;
        float4 f1 = *(const float4*)(ap + 4);
        union { struct { uint2 a, b; } u; f16x8 f; } x;
        x.u.a = pk4rtz(f0.x, f0.y, f0.z, f0.w);
        x.u.b = pk4rtz(f1.x, f1.y, f1.z, f1.w);
        adjf[in_] = x.f;
    }

    __syncthreads();

    // chain ch (0,1) = perm w*2+ch; private buffer per chain
    unsigned short* wbc[2] = { WB + (w * 2 + 0) * WBU, WB + (w * 2 + 1) * WBU };

    // h packed 2xfp16: hpk[ch][in*8+dm*2+g2] = h[i=in*16+c][d=dm*16+4q+2g2+{0,1}]
    unsigned hpk[2][16];
#pragma unroll
    for (int in_ = 0; in_ < 2; ++in_) {
        int i = in_ * 16 + c;
        int z = in_ ? zi1 : zi0;
        int pid[2];
#pragma unroll
        for (int ch = 0; ch < 2; ++ch) {
            int p = w * 2 + ch;
            pid[ch] = (i == nd0) ? c_perm[0][p] : (i == nd1) ? c_perm[1][p]
                      : (i == nd2) ? c_perm[2][p] : -1;
        }
#pragma unroll
        for (int dm = 0; dm < 4; ++dm) {
            float4 e4 = *(const float4*)(node_emb + (size_t)z * HID + dm * 16 + 4 * q);
#pragma unroll
            for (int ch = 0; ch < 2; ++ch) {
                float4 v = e4;
                if (pid[ch] >= 0) {
                    float4 f4 = *(const float4*)&idS[pid[ch] * 64 + dm * 16 + 4 * q];
                    v.x *= f4.x; v.y *= f4.y; v.z *= f4.z; v.w *= f4.w;
                }
                uint2 u = pk4rtz(v.x, v.y, v.z, v.w);
                hpk[ch][in_ * 8 + dm * 2 + 0] = u.x;
                hpk[ch][in_ * 8 + dm * 2 + 1] = u.y;
            }
        }
    }

#pragma unroll 1
    for (int l = 0; l < NLAYER; ++l) {
        // (1) h -> HB [i][d], both chains
#pragma unroll
        for (int ch = 0; ch < 2; ++ch)
#pragma unroll
            for (int in_ = 0; in_ < 2; ++in_)
#pragma unroll
                for (int dm = 0; dm < 4; ++dm)
                    *(uint2*)(wbc[ch] + (in_ * 16 + c) * SH + dm * 16 + 4 * q) =
                        make_uint2(hpk[ch][in_ * 8 + dm * 2], hpk[ch][in_ * 8 + dm * 2 + 1]);

        // (2) GEMM-A A-frags, both chains
        f16x8 hah[2][2][2];
#pragma unroll
        for (int ch = 0; ch < 2; ++ch)
#pragma unroll
            for (int im = 0; im < 2; ++im)
#pragma unroll
                for (int ks = 0; ks < 2; ++ks)
                    hah[ch][im][ks] = frd(wbc[ch] + (im * 16 + c) * SH + ks * 32 + 8 * q);

        // (3+4) GEMM-A: g = h @ W1; write GB [d'][i] (weights shared)
#pragma unroll
        for (int jn = 0; jn < 4; ++jn) {
            const unsigned short* wp = wsf + W1F + (l * 64 + jn * 16 + c) * 64;
            f16x8 b0 = gfrd(wp + 8 * q);
            f16x8 b1 = gfrd(wp + 32 + 8 * q);
#pragma unroll
            for (int ch = 0; ch < 2; ++ch) {
                f32x4 g0 = {0.f, 0.f, 0.f, 0.f}, g1 = {0.f, 0.f, 0.f, 0.f};
                g0 = MFMA16(hah[ch][0][0], b0, g0);
                g0 = MFMA16(hah[ch][0][1], b1, g0);
                g1 = MFMA16(hah[ch][1][0], b0, g1);
                g1 = MFMA16(hah[ch][1][1], b1, g1);
                *(uint2*)(wbc[ch] + (jn * 16 + c) * SG + 4 * q)      = pk4rtz(g0[0], g0[1], g0[2], g0[3]);
                *(uint2*)(wbc[ch] + (jn * 16 + c) * SG + 16 + 4 * q) = pk4rtz(g1[0], g1[1], g1[2], g1[3]);
            }
        }

        // (5) GEMM-B A-frags
        f16x8 gah[2][4];
#pragma unroll
        for (int ch = 0; ch < 2; ++ch)
#pragma unroll
            for (int dm = 0; dm < 4; ++dm)
                gah[ch][dm] = frd(wbc[ch] + (dm * 16 + c) * SG + 8 * q);

        // (6+7) GEMM-B: t^T = g^T @ adjT; t -> HB with relu(+b1)
#pragma unroll
        for (int dm = 0; dm < 4; ++dm) {
            float4 b1v = *(const float4*)&prm[(l * 4 + 0) * 64 + dm * 16 + 4 * q];
#pragma unroll
            for (int ch = 0; ch < 2; ++ch) {
                f32x4 t0 = {0.f, 0.f, 0.f, 0.f}, t1 = {0.f, 0.f, 0.f, 0.f};
                t0 = MFMA16(gah[ch][dm], adjf[0], t0);
                t1 = MFMA16(gah[ch][dm], adjf[1], t1);
                *(uint2*)(wbc[ch] + c * SH + dm * 16 + 4 * q) =
                    pk4rtz(fmaxf(t0[0] + b1v.x, 0.f), fmaxf(t0[1] + b1v.y, 0.f),
                           fmaxf(t0[2] + b1v.z, 0.f), fmaxf(t0[3] + b1v.w, 0.f));
                *(uint2*)(wbc[ch] + (16 + c) * SH + dm * 16 + 4 * q) =
                    pk4rtz(fmaxf(t1[0] + b1v.x, 0.f), fmaxf(t1[1] + b1v.y, 0.f),
                           fmaxf(t1[2] + b1v.z, 0.f), fmaxf(t1[3] + b1v.w, 0.f));
            }
        }

        // (8) GEMM-C B-frags
        f16x8 tbh[2][2][2];
#pragma unroll
        for (int ch = 0; ch < 2; ++ch)
#pragma unroll
            for (int in_ = 0; in_ < 2; ++in_)
#pragma unroll
                for (int ks = 0; ks < 2; ++ks)
                    tbh[ch][in_][ks] = frd(wbc[ch] + (in_ * 16 + c) * SH + ks * 32 + 8 * q);

        // (9+10) GEMM-C': u^T = W2^T @ t^T; LN; relu; residual
#pragma unroll
        for (int in_ = 0; in_ < 2; ++in_) {
            float v[2][16];
            float s1[2] = {0.f, 0.f}, s2[2] = {0.f, 0.f};
#pragma unroll
            for (int dm = 0; dm < 4; ++dm) {
                const unsigned short* wp2 = wsf + W2F + (l * 64 + dm * 16 + c) * 64;
                f16x8 a0 = gfrd(wp2 + 8 * q);
                f16x8 a1 = gfrd(wp2 + 32 + 8 * q);
                float4 b2v = *(const float4*)&prm[(l * 4 + 1) * 64 + dm * 16 + 4 * q];
                const float* bb = (const float*)&b2v;
#pragma unroll
                for (int ch = 0; ch < 2; ++ch) {
                    f32x4 u = {0.f, 0.f, 0.f, 0.f};
                    u = MFMA16(a0, tbh[ch][in_][0], u);
                    u = MFMA16(a1, tbh[ch][in_][1], u);
#pragma unroll
                    for (int r = 0; r < 4; ++r) {
                        float x = u[r] + bb[r];
                        v[ch][dm * 4 + r] = x;
                        s1[ch] += x;
                        s2[ch] += x * x;
                    }
                }
            }
#pragma unroll
            for (int ch = 0; ch < 2; ++ch) {
                float a1 = s1[ch], a2 = s2[ch];
                a1 += __shfl_xor(a1, 16, 64); a1 += __shfl_xor(a1, 32, 64);
                a2 += __shfl_xor(a2, 16, 64); a2 += __shfl_xor(a2, 32, 64);
                float mean = a1 * (1.0f / HID);
                float var  = a2 * (1.0f / HID) - mean * mean;
                float rs   = rsqrtf(var + 1e-5f);
#pragma unroll
                for (int dm = 0; dm < 4; ++dm) {
                    float4 gv4  = *(const float4*)&prm[(l * 4 + 2) * 64 + dm * 16 + 4 * q];
                    float4 bev4 = *(const float4*)&prm[(l * 4 + 3) * 64 + dm * 16 + 4 * q];
                    const float* gp = (const float*)&gv4;
                    const float* bp = (const float*)&bev4;
                    float y0 = fmaxf((v[ch][dm * 4 + 0] - mean) * rs * gp[0] + bp[0], 0.f);
                    float y1 = fmaxf((v[ch][dm * 4 + 1] - mean) * rs * gp[1] + bp[1], 0.f);
                    float y2 = fmaxf((v[ch][dm * 4 + 2] - mean) * rs * gp[2] + bp[2], 0.f);
                    float y3 = fmaxf((v[ch][dm * 4 + 3] - mean) * rs * gp[3] + bp[3], 0.f);
                    int i0 = in_ * 8 + dm * 2;
                    float2 h0 = upk2(hpk[ch][i0 + 0]);
                    float2 h1 = upk2(hpk[ch][i0 + 1]);
                    hpk[ch][i0 + 0] = pk2rtz(h0.x + y0, h0.y + y1);
                    hpk[ch][i0 + 1] = pk2rtz(h1.x + y2, h1.y + y3);
                }
            }
        }
    }

    // ---- dump final h (fp16 [i][d]) into per-chain buffers ----
#pragma unroll
    for (int ch = 0; ch < 2; ++ch)
#pragma unroll
        for (int in_ = 0; in_ < 2; ++in_)
#pragma unroll
            for (int dm = 0; dm < 4; ++dm)
                *(uint2*)(wbc[ch] + (in_ * 16 + c) * SH + dm * 16 + 4 * q) =
                    make_uint2(hpk[ch][in_ * 8 + dm * 2], hpk[ch][in_ * 8 + dm * 2 + 1]);
    __syncthreads();

    // ---- tail (wave 0): combine 6 perms, GEMM-D, colsum, set2, pooling ----
    if (w == 0) {
        f16x8 mah[2][2];
#pragma unroll
        for (int im = 0; im < 2; ++im) {
            float sc = ((im * 16 + c) < nn) ? (1.0f / PP) : 0.f;
#pragma unroll
            for (int ks = 0; ks < 2; ++ks) {
                int ro = (im * 16 + c) * SH + ks * 32 + 8 * q;
                float acc8[8];
#pragma unroll
                for (int j = 0; j < 8; ++j) acc8[j] = 0.f;
#pragma unroll
                for (int pv = 0; pv < 6; ++pv) {
                    f16x8 f = frd(WB + pv * WBU + ro);
#pragma unroll
                    for (int j = 0; j < 8; ++j) acc8[j] += (float)f[j];
                }
                f16x8 m;
#pragma unroll
                for (int j = 0; j < 8; ++j) m[j] = (_Float16)(acc8[j] * sc);
                mah[im][ks] = m;
            }
        }

        // GEMM-D: h1 = hm @ set1_W (m=i, n=dout)
        f32x4 hh[2][4];
#pragma unroll
        for (int im = 0; im < 2; ++im)
#pragma unroll
            for (int jn = 0; jn < 4; ++jn) hh[im][jn] = (f32x4){0.f, 0.f, 0.f, 0.f};
#pragma unroll
        for (int jn = 0; jn < 4; ++jn) {
            const unsigned short* sp = wsf + S1F + (jn * 16 + c) * 64;
            f16x8 b0 = gfrd(sp + 8 * q);
            f16x8 b1 = gfrd(sp + 32 + 8 * q);
#pragma unroll
            for (int im = 0; im < 2; ++im) {
                hh[im][jn] = MFMA16(mah[im][0], b0, hh[im][jn]);
                hh[im][jn] = MFMA16(mah[im][1], b1, hh[im][jn]);
            }
        }
        // colsum over all 32 rows (padded rows contribute relu(s1b), as ref)
#pragma unroll
        for (int jn = 0; jn < 4; ++jn) {
            float sb = s1bm[jn * 16 + c];
            float cs = 0.f;
#pragma unroll
            for (int im = 0; im < 2; ++im)
#pragma unroll
                for (int r = 0; r < 4; ++r)
                    cs += fmaxf(hh[im][jn][r] + sb, 0.f);
            cs += __shfl_xor(cs, 16, 64);
            cs += __shfl_xor(cs, 32, 64);
            if (q == 0) HSf[jn * 16 + c] = cs;
        }

        // h2 = relu(HS @ set2_W + s2b), lane = dout
        float acc = 0.f;
#pragma unroll
        for (int e4 = 0; e4 < 16; ++e4) {
            float4 wv = *(const float4*)&s2wt[lane * 64 + e4 * 4];
            float4 hv = *(const float4*)&HSf[e4 * 4];
            acc += hv.x * wv.x + hv.y * wv.y + hv.z * wv.z + hv.w * wv.w;
        }
        float h2 = fmaxf(acc + s2bm[lane], 0.f);

        // pooling fold: device-scope atomicMax (h2 >= 0: uint order == float order)
        atomicMax(&gmax[b * HID + lane], __float_as_uint(h2));
        __threadfence();
        unsigned old = 0;
        if (lane == 0) old = atomicAdd(&cnt[b], 1u);
        old = __shfl(old, 0, 64);
        if (old == NS - 1) {   // last of the 32 subgraph-writers of this graph
            __threadfence();
            unsigned mbits = atomicOr(&gmax[b * HID + lane], 0u);
            float v = __uint_as_float(mbits) * outw[lane];
#pragma unroll
            for (int off = 32; off > 0; off >>= 1) v += __shfl_xor(v, off, 64);
            if (lane == 0) out[b] = v + outb[0];
        }
    }
}

extern "C" void kernel_launch(void* const* d_in, const int* in_sizes, int n_in,
                              void* d_out, int out_size, void* d_ws, size_t ws_size,
                              hipStream_t stream)
{
    const int*   xg       = (const int*)d_in[0];
    const float* subadj   = (const float*)d_in[1];
    const int*   subgs    = (const int*)d_in[2];
    const int*   num_node = (const int*)d_in[3];
    const float* idemb    = (const float*)d_in[5];
    const float* node_emb = (const float*)d_in[6];
    const float* w1       = (const float*)d_in[7];
    const float* b1       = (const float*)d_in[8];
    const float* w2       = (const float*)d_in[9];
    const float* b2       = (const float*)d_in[10];
    const float* g        = (const float*)d_in[11];
    const float* be       = (const float*)d_in[12];
    const float* s1w      = (const float*)d_in[13];
    const float* s1b      = (const float*)d_in[14];
    const float* s2w      = (const float*)d_in[15];
    const float* s2b      = (const float*)d_in[16];
    const float* outw     = (const float*)d_in[17];
    const float* outb     = (const float*)d_in[18];

    char* ws = (char*)d_ws;
    unsigned short* wsf = (unsigned short*)ws;
    const float* s2wt = (const float*)(ws + S2WT_BYTE);
    unsigned* gmax = (unsigned*)(ws + GMAX_BYTE);
    unsigned* cnt  = (unsigned*)(ws + CNT_BYTE);

    idmpnn_prep<<<12, 256, 0, stream>>>(w1, w2, s1w, s2w, ws);
    idmpnn_main<<<STOT, 192, 0, stream>>>(xg, subadj, subgs, num_node,
                                          idemb, node_emb,
                                          b1, b2, g, be, s1b, s2b, outw, outb,
                                          wsf, s2wt, gmax, cnt, (float*)d_out);
}